// Round 5
// baseline (128.037 us; speedup 1.0000x reference)
//
#include <hip/hip_runtime.h>
#include <math.h>

typedef float f4 __attribute__((ext_vector_type(4)));

#define BDIM 256
#define WPB 4                     // waves per block
#define RPW 4                     // rows per wave
#define ROWS_PER_BLOCK (WPB * RPW)   // 16
#define WAVE_F4 300               // f4 per tensor per wave chunk (4 rows * 75)

typedef __attribute__((address_space(1))) const unsigned int glob_u32;
typedef __attribute__((address_space(3))) unsigned int lds_u32;

__device__ __forceinline__ void gload16(const f4* g, f4* l) {
    // async global->LDS DMA, 16B/lane; LDS dest = wave-uniform base + lane*16
    __builtin_amdgcn_global_load_lds((glob_u32*)g, (lds_u32*)l, 16, 0, 0);
}

__device__ __forceinline__ float dot4(f4 a, f4 w) {
    return a[0]*w[0] + a[1]*w[1] + a[2]*w[2] + a[3]*w[3];
}

__global__ __launch_bounds__(BDIM) void taskselector_kernel(
    const f4* __restrict__ se1,
    const f4* __restrict__ se2,
    const float* __restrict__ W,
    const float* __restrict__ bvec,
    const f4* __restrict__ u4,
    f4* __restrict__ out)
{
    // per-wave LDS slices; waves never share -> no __syncthreads anywhere
    __shared__ f4 L1[WPB][WAVE_F4];    // 19200 B
    __shared__ f4 L2[WPB][WAVE_F4];    // 19200 B

    const int tid  = threadIdx.x;
    const int lane = tid & 63;
    const int wave = tid >> 6;
    const int rowbase = blockIdx.x * ROWS_PER_BLOCK + wave * RPW;

    f4* Lw1 = &L1[wave][0];
    f4* Lw2 = &L2[wave][0];

    // ---- issue async global->LDS for this wave's 4-row chunk (both tensors) ----
    const f4* g1 = se1 + (size_t)rowbase * 75;
    const f4* g2 = se2 + (size_t)rowbase * 75;
    #pragma unroll
    for (int k = 0; k < 4; k++) gload16(g1 + k * 64 + lane, Lw1 + k * 64);
    if (lane < 44)              gload16(g1 + 256 + lane,    Lw1 + 256);
    #pragma unroll
    for (int k = 0; k < 4; k++) gload16(g2 + k * 64 + lane, Lw2 + k * 64);
    if (lane < 44)              gload16(g2 + 256 + lane,    Lw2 + 256);

    // ---- W / b / u into regs while DMA is in flight ----
    const bool extra = (lane < 11);
    const f4 zero = (f4)0.f;
    const f4* W0 = (const f4*)W;
    const f4* W1 = (const f4*)(W + 600);
    f4 w0a = W0[lane];
    f4 w0b = extra ? W0[64 + lane]  : zero;
    f4 w0c = W0[75 + lane];
    f4 w0d = extra ? W0[139 + lane] : zero;
    f4 w1a = W1[lane];
    f4 w1b = extra ? W1[64 + lane]  : zero;
    f4 w1c = W1[75 + lane];
    f4 w1d = extra ? W1[139 + lane] : zero;
    const float b0 = bvec[0];
    const float b1 = bvec[1];
    const f4 ua = u4[rowbase / 2];       // u for rows rowbase..rowbase+1
    const f4 ub = u4[rowbase / 2 + 1];   // rows rowbase+2..rowbase+3

    // wait for this wave's own DMA only (vmcnt is per-wave; no cross-wave sync)
    asm volatile("s_waitcnt vmcnt(0)" ::: "memory");

    // ---- per-row selector computation (identical math to proven absmax-0 version) ----
    float s0r[1], dummy; (void)dummy; (void)s0r;
    float sA0, sA1, sB0, sB1, sC0, sC1, sD0, sD1;
    #pragma unroll
    for (int r = 0; r < RPW; r++) {
        f4 a0 = Lw1[r * 75 + lane];
        f4 c0 = Lw2[r * 75 + lane];
        f4 a1 = extra ? Lw1[r * 75 + 64 + lane] : zero;
        f4 c1 = extra ? Lw2[r * 75 + 64 + lane] : zero;
        float d0 = dot4(a0, w0a) + dot4(a1, w0b) + dot4(c0, w0c) + dot4(c1, w0d);
        float d1 = dot4(a0, w1a) + dot4(a1, w1b) + dot4(c0, w1c) + dot4(c1, w1d);
        #pragma unroll
        for (int off = 32; off > 0; off >>= 1) {
            d0 += __shfl_xor(d0, off, 64);
            d1 += __shfl_xor(d1, off, 64);
        }
        float z0 = fmaxf(d0 + b0, 0.f);
        float z1 = fmaxf(d1 + b1, 0.f);
        float m  = fmaxf(z0, z1);
        float lse = m + logf(expf(z0 - m) + expf(z1 - m));
        float uu0 = (r < 2) ? ((r == 0) ? ua[0] : ua[2]) : ((r == 2) ? ub[0] : ub[2]);
        float uu1 = (r < 2) ? ((r == 0) ? ua[1] : ua[3]) : ((r == 2) ? ub[1] : ub[3]);
        float q0 = (z0 - lse) + (-logf(-logf(uu0 + 1e-20f) + 1e-20f));
        float q1 = (z1 - lse) + (-logf(-logf(uu1 + 1e-20f) + 1e-20f));
        float mm = fmaxf(q0, q1);
        float e0 = expf(q0 - mm);
        float e1 = expf(q1 - mm);
        float s  = e0 + e1;
        float y0 = e0 / s;
        float y1 = e1 / s;
        bool  pick0 = (q0 >= q1);               // argmax, first index wins ties
        float s0 = pick0 ? ((1.f - y0) + y0) : 0.f;
        float s1 = pick0 ? 0.f : ((1.f - y1) + y1);
        if (r == 0) { sA0 = s0; sA1 = s1; }
        else if (r == 1) { sB0 = s0; sB1 = s1; }
        else if (r == 2) { sC0 = s0; sC1 = s1; }
        else { sD0 = s0; sD1 = s1; }
    }

    // ---- flat, 128B-aligned nontemporal store of this wave's out chunk ----
    // out chunk = 600 f4 (9600 B, chunk start ≡ 0 mod 128)
    f4* o = out + (size_t)rowbase * 150;
    #pragma unroll
    for (int k = 0; k < 10; k++) {
        const int j = k * 64 + lane;            // 0..639; valid < 600
        if (k == 9 && lane >= 24) break;
        const int row = j / 150;                // 0..3
        const int rem = j - row * 150;
        const bool first = (rem < 75);
        f4 v = first ? Lw1[row * 75 + rem] : Lw2[row * 75 + rem - 75];
        // cndmask chain (no register-array runtime indexing)
        float sf = (row < 2) ? ((row == 0) ? sA0 : sB0) : ((row == 2) ? sC0 : sD0);
        float ss = (row < 2) ? ((row == 0) ? sA1 : sB1) : ((row == 2) ? sC1 : sD1);
        float sc = first ? sf : ss;
        __builtin_nontemporal_store(v * sc, o + j);
    }
}

extern "C" void kernel_launch(void* const* d_in, const int* in_sizes, int n_in,
                              void* d_out, int out_size, void* d_ws, size_t ws_size,
                              hipStream_t stream) {
    const f4* se1 = (const f4*)d_in[0];
    const f4* se2 = (const f4*)d_in[1];
    const float* W = (const float*)d_in[2];
    const float* b = (const float*)d_in[3];
    const f4* u4  = (const f4*)d_in[4];
    f4* out = (f4*)d_out;

    const int Brows = in_sizes[0] / 300;          // 131072
    const int nblocks = Brows / ROWS_PER_BLOCK;   // 8192 (exact)

    taskselector_kernel<<<nblocks, BDIM, 0, stream>>>(se1, se2, W, b, u4, out);
}

// Round 7
// 110.139 us; speedup vs baseline: 1.1625x; 1.1625x over previous
//
#include <hip/hip_runtime.h>
#include <math.h>

typedef float f4 __attribute__((ext_vector_type(4)));

#define BDIM 256
#define TROWS 8                  // rows per tile: 8*1200B = 9600B ≡ 0 (mod 128)
#define TILE_F4_IN 600           // per-tensor f4 per tile (8*300/4)
#define TILE_F4_OUT 1200         // out f4 per tile (8*600/4)

__device__ __forceinline__ float dot4(f4 a, f4 w) {
    return a[0]*w[0] + a[1]*w[1] + a[2]*w[2] + a[3]*w[3];
}

__global__ __launch_bounds__(BDIM, 6) void taskselector_kernel(
    const f4* __restrict__ se1,
    const f4* __restrict__ se2,
    const float* __restrict__ W,
    const float* __restrict__ bvec,
    const f4* __restrict__ u4,
    f4* __restrict__ out)
{
    __shared__ f4 L1[TILE_F4_IN];      // 9600 B
    __shared__ f4 L2[TILE_F4_IN];      // 9600 B
    __shared__ float SEL[TROWS * 2];   // 64 B
    __shared__ f4 UL[TROWS / 2];       // 16 floats of u (2 per row, 8 rows)

    const int tid  = threadIdx.x;
    const int lane = tid & 63;
    const int wave = tid >> 6;
    const int tile = blockIdx.x;

    // ---- issue the tile's global loads first (latency in flight) ----
    const f4* s1 = se1 + (size_t)tile * TILE_F4_IN;
    const f4* s2 = se2 + (size_t)tile * TILE_F4_IN;
    const f4 zero = (f4)0.f;
    const bool t3 = (tid < TILE_F4_IN - 2 * BDIM);   // 88 threads
    f4 t0 = __builtin_nontemporal_load(s1 + tid);
    f4 t1 = __builtin_nontemporal_load(s1 + BDIM + tid);
    f4 t2 = t3 ? __builtin_nontemporal_load(s1 + 2 * BDIM + tid) : zero;
    f4 q0 = __builtin_nontemporal_load(s2 + tid);
    f4 q1 = __builtin_nontemporal_load(s2 + BDIM + tid);
    f4 q2 = t3 ? __builtin_nontemporal_load(s2 + 2 * BDIM + tid) : zero;
    if (tid < TROWS / 2) UL[tid] = u4[(size_t)tile * (TROWS / 2) + tid];

    // ---- W / b into regs while loads are in flight ----
    const bool extra = (lane < 11);
    const f4* W0 = (const f4*)W;
    const f4* W1 = (const f4*)(W + 600);
    f4 w0a = W0[lane];
    f4 w0b = extra ? W0[64 + lane]  : zero;
    f4 w0c = W0[75 + lane];
    f4 w0d = extra ? W0[139 + lane] : zero;
    f4 w1a = W1[lane];
    f4 w1b = extra ? W1[64 + lane]  : zero;
    f4 w1c = W1[75 + lane];
    f4 w1d = extra ? W1[139 + lane] : zero;
    const float b0 = bvec[0];
    const float b1 = bvec[1];

    // ---- stage to LDS ----
    L1[tid] = t0;
    L1[BDIM + tid] = t1;
    L2[tid] = q0;
    L2[BDIM + tid] = q1;
    if (t3) {
        L1[2 * BDIM + tid] = t2;
        L2[2 * BDIM + tid] = q2;
    }
    __syncthreads();

    // ---- compute selectors: wave w -> rows {2w, 2w+1} ----
    const float* ULf = (const float*)UL;
    #pragma unroll
    for (int rr = 0; rr < 2; rr++) {
        const int r = wave * 2 + rr;
        const f4* R1 = L1 + r * 75;
        const f4* R2 = L2 + r * 75;
        f4 a0 = R1[lane];
        f4 c0 = R2[lane];
        f4 a1 = extra ? R1[64 + lane] : zero;
        f4 c1 = extra ? R2[64 + lane] : zero;
        float d0 = dot4(a0, w0a) + dot4(a1, w0b) + dot4(c0, w0c) + dot4(c1, w0d);
        float d1 = dot4(a0, w1a) + dot4(a1, w1b) + dot4(c0, w1c) + dot4(c1, w1d);
        #pragma unroll
        for (int off = 32; off > 0; off >>= 1) {
            d0 += __shfl_xor(d0, off, 64);
            d1 += __shfl_xor(d1, off, 64);
        }
        // epilogue — identical formula to the proven (absmax 0.0) version
        float z0 = fmaxf(d0 + b0, 0.f);
        float z1 = fmaxf(d1 + b1, 0.f);
        float m  = fmaxf(z0, z1);
        float lse = m + logf(expf(z0 - m) + expf(z1 - m));
        float uu0 = ULf[2 * r];
        float uu1 = ULf[2 * r + 1];
        float q0v = (z0 - lse) + (-logf(-logf(uu0 + 1e-20f) + 1e-20f));
        float q1v = (z1 - lse) + (-logf(-logf(uu1 + 1e-20f) + 1e-20f));
        float mm = fmaxf(q0v, q1v);
        float e0 = expf(q0v - mm);
        float e1 = expf(q1v - mm);
        float s  = e0 + e1;
        float y0 = e0 / s;
        float y1 = e1 / s;
        bool  pick0 = (q0v >= q1v);             // argmax, first index wins ties
        float s0 = pick0 ? ((1.f - y0) + y0) : 0.f;
        float s1v = pick0 ? 0.f : ((1.f - y1) + y1);
        if (lane == 0) { SEL[2 * r] = s0; SEL[2 * r + 1] = s1v; }
    }
    __syncthreads();

    // ---- gated store: flat, 128B-aligned, full lines only ----
    f4* o = out + (size_t)tile * TILE_F4_OUT;
    #pragma unroll
    for (int k = 0; k < 4; k++) {
        const int j   = k * BDIM + tid;
        const int row = j / 150;
        const int rem = j - row * 150;
        const bool first = (rem < 75);
        f4 v = first ? L1[row * 75 + rem] : L2[row * 75 + rem - 75];
        float sc = SEL[2 * row + (first ? 0 : 1)];
        __builtin_nontemporal_store(v * sc, o + j);
    }
    if (tid < TILE_F4_OUT - 4 * BDIM) {        // 176 threads
        const int j   = 4 * BDIM + tid;
        const int row = j / 150;
        const int rem = j - row * 150;
        const bool first = (rem < 75);
        f4 v = first ? L1[row * 75 + rem] : L2[row * 75 + rem - 75];
        float sc = SEL[2 * row + (first ? 0 : 1)];
        __builtin_nontemporal_store(v * sc, o + j);
    }
}

extern "C" void kernel_launch(void* const* d_in, const int* in_sizes, int n_in,
                              void* d_out, int out_size, void* d_ws, size_t ws_size,
                              hipStream_t stream) {
    const f4* se1 = (const f4*)d_in[0];
    const f4* se2 = (const f4*)d_in[1];
    const float* W = (const float*)d_in[2];
    const float* b = (const float*)d_in[3];
    const f4* u4  = (const f4*)d_in[4];
    f4* out = (f4*)d_out;

    const int Brows = in_sizes[0] / 300;     // 131072
    const int ntiles = Brows / TROWS;        // 16384 (exact for this problem)

    taskselector_kernel<<<ntiles, BDIM, 0, stream>>>(se1, se2, W, b, u4, out);
}